// Round 13
// baseline (292.548 us; speedup 1.0000x reference)
//
#include <hip/hip_runtime.h>

#define TT 256
#define BB 512
#define DD 128
#define HH 50
#define KK 5
#define AA 4
#define NROW 131072      // T*B rows

#define R25(X) X(0) X(1) X(2) X(3) X(4) X(5) X(6) X(7) X(8) X(9) \
  X(10) X(11) X(12) X(13) X(14) X(15) X(16) X(17) X(18) X(19) \
  X(20) X(21) X(22) X(23) X(24)

typedef _Float16 half4 __attribute__((ext_vector_type(4)));
typedef float f32x4 __attribute__((ext_vector_type(4)));

// ---------------- K0: weight prep ----------------
__global__ void k0_prep(const float* __restrict__ W_in,
                        const float* __restrict__ W_ctx,
                        const float* __restrict__ W_key,
                        const float* __restrict__ W_q,
                        const float* __restrict__ b_key,
                        const float* __restrict__ b_q,
                        float* __restrict__ WT, float* __restrict__ WHT,
                        float* __restrict__ WK2T, float* __restrict__ bias2) {
  int i = blockIdx.x * 256 + threadIdx.x;
  if (i < DD * 52) {
    int j = i / 52, h = i % 52;
    WT[i] = (h < HH) ? W_in[h * DD + j] : 0.f;
  }
  if (i < HH * 52) {
    int j = i / 52, h = i % 52;
    WHT[i] = (h < HH) ? W_ctx[h * (2 * HH) + HH + j] : 0.f;
  }
  if (i < HH * 64) {
    int j = i >> 6, l = i & 63;
    float v = 0.f;
    if (l < HH) v = W_ctx[l * (2 * HH) + j];
    else if (l < HH + KK) v = W_key[(l - HH) * HH + j];
    else if (l < HH + 2 * KK) v = W_q[(l - HH - KK) * HH + j];
    WK2T[i] = v;
  }
  if (i < 64) {
    float bv = 0.f;
    if (i >= HH && i < HH + KK) bv = b_key[i - HH];
    else if (i >= HH + KK && i < HH + 2 * KK) bv = b_q[i - HH - KK];
    bias2[i] = bv;
  }
}

// ---------------- K1a: h = relu(x@W_in^T + b_in), 2 passes x 25 accums ----
__global__ __launch_bounds__(256) void k1a(const float* __restrict__ x,
                                           const float* __restrict__ WT,
                                           const float* __restrict__ b_in,
                                           float* __restrict__ hT) {
  __shared__ float xs[256 * 17];
  const int tid = threadIdx.x;
  const int row = blockIdx.x * 256 + tid;
  const float* __restrict__ xblk = x + (size_t)blockIdx.x * 256 * DD;

#pragma unroll 1
  for (int hp = 0; hp < 2; ++hp) {
    const int hb = hp * 25;
#define DECLA(i) float a##i = b_in[hb + i];
    R25(DECLA)

#pragma unroll 1
    for (int jb = 0; jb < 8; ++jb) {
      __syncthreads();
#pragma unroll
      for (int u = 0; u < 4; ++u) {
        const int f = tid + u * 256;
        const int r = f >> 2, c4 = f & 3;
        const float4 v = *reinterpret_cast<const float4*>(
            xblk + (size_t)r * DD + jb * 16 + c4 * 4);
        float* d = &xs[r * 17 + c4 * 4];
        d[0] = v.x; d[1] = v.y; d[2] = v.z; d[3] = v.w;
      }
      __syncthreads();
      const float* __restrict__ xrow = &xs[tid * 17];
#pragma unroll
      for (int cc = 0; cc < 16; cc += 4) {
        const int j = jb * 16 + cc;
        const float xv0 = xrow[cc + 0];
        const float xv1 = xrow[cc + 1];
        const float xv2 = xrow[cc + 2];
        const float xv3 = xrow[cc + 3];
        const float* __restrict__ w0 = WT + (j + 0) * 52 + hb;
        const float* __restrict__ w1 = WT + (j + 1) * 52 + hb;
        const float* __restrict__ w2 = WT + (j + 2) * 52 + hb;
        const float* __restrict__ w3 = WT + (j + 3) * 52 + hb;
#define FMA25(i)                  \
  a##i = fmaf(xv0, w0[i], a##i);  \
  a##i = fmaf(xv1, w1[i], a##i);  \
  a##i = fmaf(xv2, w2[i], a##i);  \
  a##i = fmaf(xv3, w3[i], a##i);
        R25(FMA25)
      }
    }

#define STA(i) hT[(size_t)(hb + i) * NROW + row] = fmaxf(a##i, 0.f);
    R25(STA)
  }
}

// ---------------- K1b: g = h @ Wh^T + b_ctx -> f16, fragment-ordered -------
// gh[(b*TT + t)*64 + h] (_Float16), slots 50-63 zeroed.
__global__ __launch_bounds__(256) void k1b(const float* __restrict__ hT,
                                           const float* __restrict__ WHT,
                                           const float* __restrict__ b_ctx,
                                           _Float16* __restrict__ gh) {
  const int row = blockIdx.x * 256 + threadIdx.x;
  const int b = row & (BB - 1);
  const int t = row >> 9;
  _Float16* __restrict__ gr = gh + ((size_t)b * TT + t) * 64;

#pragma unroll 1
  for (int gp = 0; gp < 2; ++gp) {
    const int gb = gp * 25;
#define DECLG(i) float a##i = b_ctx[gb + i];
    R25(DECLG)

#pragma unroll 5
    for (int s = 0; s < HH; ++s) {
      const float hv = hT[(size_t)s * NROW + row];
      const float* __restrict__ wh = WHT + s * 52 + gb;
#define GFMA(i) a##i = fmaf(hv, wh[i], a##i);
      R25(GFMA)
    }

#define H4(p, q, r, s) \
  { half4 v; v[0] = (_Float16)(p); v[1] = (_Float16)(q); \
    v[2] = (_Float16)(r); v[3] = (_Float16)(s); \
    *reinterpret_cast<half4*>(gr + _slot) = v; }
    if (gp == 0) {  // h 0..24 -> slots 0..24
      int _slot;
      _slot = 0;  H4(a0, a1, a2, a3)
      _slot = 4;  H4(a4, a5, a6, a7)
      _slot = 8;  H4(a8, a9, a10, a11)
      _slot = 12; H4(a12, a13, a14, a15)
      _slot = 16; H4(a16, a17, a18, a19)
      _slot = 20; H4(a20, a21, a22, a23)
      gr[24] = (_Float16)a24;
    } else {  // h 25..49 -> slots 25..49; zero 50..63
      int _slot;
      gr[25] = (_Float16)a0;
      gr[26] = (_Float16)a1;
      gr[27] = (_Float16)a2;
      _slot = 28; H4(a3, a4, a5, a6)
      _slot = 32; H4(a7, a8, a9, a10)
      _slot = 36; H4(a11, a12, a13, a14)
      _slot = 40; H4(a15, a16, a17, a18)
      _slot = 44; H4(a19, a20, a21, a22)
      gr[48] = (_Float16)a23;
      gr[49] = (_Float16)a24;
      gr[50] = (_Float16)0.f;
      gr[51] = (_Float16)0.f;
      _slot = 52; H4(0.f, 0.f, 0.f, 0.f)
      _slot = 56; H4(0.f, 0.f, 0.f, 0.f)
      _slot = 60; H4(0.f, 0.f, 0.f, 0.f)
    }
  }
}

// ---------------- K2: MFMA-batched recurrence (32 blocks x 1 wave) ---------
// Wave evolves 16 chains: c^T_{t+1} = relu(A·c^T_t + g^T_t), A = WK2T^T
// (rows 0-49 Wc, 50-54 W_key, 55-59 W_q). D-frag == next B-frag (verified
// identity), so the recurrence's all-to-all runs inside the matrix unit:
// no LDS, no shuffles. A cols >=50 are zero -> junk rows annihilate.
__global__ __launch_bounds__(64, 1) void k2_mfma(
    const _Float16* __restrict__ gh, const float* __restrict__ WK2T,
    const float* __restrict__ bias2, const float* __restrict__ fc,
    float* __restrict__ ctxg, float* __restrict__ kqg) {
  const int lane = threadIdx.x;
  const int lrow = lane & 15, lgrp = lane >> 4;
  const int chain = blockIdx.x * 16 + lrow;

#define DECLWF(m, kk)                                                       \
  half4 wf_##m##_##kk;                                                      \
  {                                                                         \
    const int j0 = (kk) * 16 + 4 * lgrp;                                    \
    wf_##m##_##kk[0] = (_Float16)((j0 + 0 < HH) ? WK2T[(j0 + 0) * 64 + (m) * 16 + lrow] : 0.f); \
    wf_##m##_##kk[1] = (_Float16)((j0 + 1 < HH) ? WK2T[(j0 + 1) * 64 + (m) * 16 + lrow] : 0.f); \
    wf_##m##_##kk[2] = (_Float16)((j0 + 2 < HH) ? WK2T[(j0 + 2) * 64 + (m) * 16 + lrow] : 0.f); \
    wf_##m##_##kk[3] = (_Float16)((j0 + 3 < HH) ? WK2T[(j0 + 3) * 64 + (m) * 16 + lrow] : 0.f); \
  }
  DECLWF(0, 0) DECLWF(0, 1) DECLWF(0, 2) DECLWF(0, 3)
  DECLWF(1, 0) DECLWF(1, 1) DECLWF(1, 2) DECLWF(1, 3)
  DECLWF(2, 0) DECLWF(2, 1) DECLWF(2, 2) DECLWF(2, 3)
  DECLWF(3, 0) DECLWF(3, 1) DECLWF(3, 2) DECLWF(3, 3)

  // m=3 rows: 48 + 4*lgrp + r; key/q rows 50-59 -> kqg slot row-50
  const float bias_0 = bias2[48 + 4 * lgrp + 0];
  const float bias_1 = bias2[48 + 4 * lgrp + 1];
  const float bias_2 = bias2[48 + 4 * lgrp + 2];
  const float bias_3 = bias2[48 + 4 * lgrp + 3];
#define KQB(r)                                                         \
  const int row_##r = 48 + 4 * lgrp + r;                               \
  const bool kv_##r = (row_##r >= 50 && row_##r < 60);                 \
  float* kqb_##r =                                                     \
      kqg + ((size_t)chain * 10 + (kv_##r ? row_##r - 50 : 0)) * 257;
  KQB(0) KQB(1) KQB(2) KQB(3)

#define DECLBF(kk)                                                  \
  half4 bf_##kk;                                                    \
  {                                                                 \
    const int j0 = (kk) * 16 + 4 * lgrp;                            \
    bf_##kk[0] = (_Float16)((j0 + 0 < HH) ? fc[j0 + 0] : 0.f);      \
    bf_##kk[1] = (_Float16)((j0 + 1 < HH) ? fc[j0 + 1] : 0.f);      \
    bf_##kk[2] = (_Float16)((j0 + 2 < HH) ? fc[j0 + 2] : 0.f);      \
    bf_##kk[3] = (_Float16)((j0 + 3 < HH) ? fc[j0 + 3] : 0.f);      \
  }
  DECLBF(0) DECLBF(1) DECLBF(2) DECLBF(3)

  // ctx[t=0] = c0 for this block's 16 chains
  for (int i = lane; i < 16 * HH; i += 64) {
    const int c = i / HH, h = i - c * HH;
    ctxg[((size_t)(blockIdx.x * 16 + c) * 257 + 0) * HH + h] = fc[h];
  }

  float* __restrict__ ctp = ctxg + (size_t)chain * 257 * HH + 4 * lgrp;
  const _Float16* __restrict__ ghp =
      gh + (size_t)chain * TT * 64 + 4 * lgrp;

  half4 gA0 = *(const half4*)(ghp + 0 * 64 + 0);
  half4 gA1 = *(const half4*)(ghp + 0 * 64 + 16);
  half4 gA2 = *(const half4*)(ghp + 0 * 64 + 32);
  half4 gA3 = *(const half4*)(ghp + 0 * 64 + 48);
  half4 gB0 = *(const half4*)(ghp + 1 * 64 + 0);
  half4 gB1 = *(const half4*)(ghp + 1 * 64 + 16);
  half4 gB2 = *(const half4*)(ghp + 1 * 64 + 32);
  half4 gB3 = *(const half4*)(ghp + 1 * 64 + 48);

  const f32x4 zf = {0.f, 0.f, 0.f, 0.f};

#define MM(D, A, B) D = __builtin_amdgcn_mfma_f32_16x16x16f16(A, B, D, 0, 0, 0);
#define MSTEP(T, G0, G1, G2, G3, TPF)                                      \
  {                                                                        \
    f32x4 d0 = zf, d1 = zf, d2 = zf, d3 = zf;                              \
    MM(d0, wf_0_0, bf_0) MM(d1, wf_1_0, bf_0)                              \
    MM(d2, wf_2_0, bf_0) MM(d3, wf_3_0, bf_0)                              \
    MM(d0, wf_0_1, bf_1) MM(d1, wf_1_1, bf_1)                              \
    MM(d2, wf_2_1, bf_1) MM(d3, wf_3_1, bf_1)                              \
    MM(d0, wf_0_2, bf_2) MM(d1, wf_1_2, bf_2)                              \
    MM(d2, wf_2_2, bf_2) MM(d3, wf_3_2, bf_2)                              \
    MM(d0, wf_0_3, bf_3) MM(d1, wf_1_3, bf_3)                              \
    MM(d2, wf_2_3, bf_3) MM(d3, wf_3_3, bf_3)                              \
    if (kv_0) kqb_0[T] = d3[0] + bias_0;                                   \
    if (kv_1) kqb_1[T] = d3[1] + bias_1;                                   \
    if (kv_2) kqb_2[T] = d3[2] + bias_2;                                   \
    if (kv_3) kqb_3[T] = d3[3] + bias_3;                                   \
    const float cn_0_0 = fmaxf(d0[0] + (float)G0[0], 0.f);                 \
    const float cn_0_1 = fmaxf(d0[1] + (float)G0[1], 0.f);                 \
    const float cn_0_2 = fmaxf(d0[2] + (float)G0[2], 0.f);                 \
    const float cn_0_3 = fmaxf(d0[3] + (float)G0[3], 0.f);                 \
    const float cn_1_0 = fmaxf(d1[0] + (float)G1[0], 0.f);                 \
    const float cn_1_1 = fmaxf(d1[1] + (float)G1[1], 0.f);                 \
    const float cn_1_2 = fmaxf(d1[2] + (float)G1[2], 0.f);                 \
    const float cn_1_3 = fmaxf(d1[3] + (float)G1[3], 0.f);                 \
    const float cn_2_0 = fmaxf(d2[0] + (float)G2[0], 0.f);                 \
    const float cn_2_1 = fmaxf(d2[1] + (float)G2[1], 0.f);                 \
    const float cn_2_2 = fmaxf(d2[2] + (float)G2[2], 0.f);                 \
    const float cn_2_3 = fmaxf(d2[3] + (float)G2[3], 0.f);                 \
    const float cn_3_0 = fmaxf(d3[0] + (float)G3[0], 0.f);                 \
    const float cn_3_1 = fmaxf(d3[1] + (float)G3[1], 0.f);                 \
    const float cn_3_2 = fmaxf(d3[2] + (float)G3[2], 0.f);                 \
    const float cn_3_3 = fmaxf(d3[3] + (float)G3[3], 0.f);                 \
    G0 = *(const half4*)(ghp + (size_t)((TPF) < TT ? (TPF) : TT - 1) * 64 + 0);  \
    G1 = *(const half4*)(ghp + (size_t)((TPF) < TT ? (TPF) : TT - 1) * 64 + 16); \
    G2 = *(const half4*)(ghp + (size_t)((TPF) < TT ? (TPF) : TT - 1) * 64 + 32); \
    G3 = *(const half4*)(ghp + (size_t)((TPF) < TT ? (TPF) : TT - 1) * 64 + 48); \
    float* ctp2 = ctp + (size_t)((T) + 1) * HH;                            \
    ctp2[0] = cn_0_0;  ctp2[1] = cn_0_1;                                   \
    ctp2[2] = cn_0_2;  ctp2[3] = cn_0_3;                                   \
    ctp2[16] = cn_1_0; ctp2[17] = cn_1_1;                                  \
    ctp2[18] = cn_1_2; ctp2[19] = cn_1_3;                                  \
    ctp2[32] = cn_2_0; ctp2[33] = cn_2_1;                                  \
    ctp2[34] = cn_2_2; ctp2[35] = cn_2_3;                                  \
    if (lgrp == 0) { ctp2[48] = cn_3_0; ctp2[49] = cn_3_1; }               \
    bf_0[0] = (_Float16)cn_0_0; bf_0[1] = (_Float16)cn_0_1;                \
    bf_0[2] = (_Float16)cn_0_2; bf_0[3] = (_Float16)cn_0_3;                \
    bf_1[0] = (_Float16)cn_1_0; bf_1[1] = (_Float16)cn_1_1;                \
    bf_1[2] = (_Float16)cn_1_2; bf_1[3] = (_Float16)cn_1_3;                \
    bf_2[0] = (_Float16)cn_2_0; bf_2[1] = (_Float16)cn_2_1;                \
    bf_2[2] = (_Float16)cn_2_2; bf_2[3] = (_Float16)cn_2_3;                \
    bf_3[0] = (_Float16)cn_3_0; bf_3[1] = (_Float16)cn_3_1;                \
    bf_3[2] = (_Float16)cn_3_2; bf_3[3] = (_Float16)cn_3_3;                \
  }

#pragma unroll 1
  for (int t = 0; t < TT; t += 2) {
    MSTEP(t, gA0, gA1, gA2, gA3, t + 2)
    MSTEP(t + 1, gB0, gB1, gB2, gB3, t + 3)
  }

  {  // tail: key/q of c_TT at index TT
    f32x4 d3 = zf;
    MM(d3, wf_3_0, bf_0) MM(d3, wf_3_1, bf_1)
    MM(d3, wf_3_2, bf_2) MM(d3, wf_3_3, bf_3)
    if (kv_0) kqb_0[TT] = d3[0] + bias_0;
    if (kv_1) kqb_1[TT] = d3[1] + bias_1;
    if (kv_2) kqb_2[TT] = d3[2] + bias_2;
    if (kv_3) kqb_3[TT] = d3[3] + bias_3;
  }
}

// ---------------- K3: MFMA flash attention, LDS-staged ---------------------
// keys: kqg[b][k][s] (k 0-4); q for step t: kqg[b][5+k][t+1].
__global__ __launch_bounds__(256, 4) void k3_attn(
    const float* __restrict__ ctxg, const float* __restrict__ kqg,
    const float* __restrict__ W_act, const float* __restrict__ b_act,
    float* __restrict__ out) {
  __shared__ __align__(16) float ct[64 * 66];   // [s_local][h]
  __shared__ __align__(16) float k_l[8 * 68];   // [k][s_local], rows 5-7 = 0
  __shared__ __align__(16) float o_l[64 * 66];  // [t_local][h]
  __shared__ float su_l[64];

  const int tid = threadIdx.x;
  const int bid = blockIdx.x;
  const int chunk = 3 - (bid >> 9);  // heavy-first
  const int b = bid & 511;
  const int tbase = chunk * 64;
  const int nst = min(tbase + 66, 257);
  const int ntiles = (nst + 63) >> 6;
  const int wave = tid >> 6;
  const int lane = tid & 63;
  const int lrow = lane & 15;
  const int lgrp = lane >> 4;
  const int tw = tbase + wave * 16;

  if (tid < 3 * 68) k_l[5 * 68 + tid] = 0.f;

  half4 qf;
#pragma unroll
  for (int i = 0; i < 4; ++i) {
    const int k = 4 * lgrp + i;
    qf[i] = (_Float16)((k < KK)
                           ? kqg[((size_t)b * 10 + 5 + k) * 257 + tw + lrow + 1]
                           : 0.f);
  }

  const f32x4 zf = {0.f, 0.f, 0.f, 0.f};
  f32x4 acc0 = zf, acc1 = zf, acc2 = zf, acc3 = zf;
  float su = 0.f;

#pragma unroll 1
  for (int tile = 0; tile < ntiles; ++tile) {
    __syncthreads();
    {
      const int r = tid >> 2;
      const int c0 = (tid & 3) * 16;
      const int srow = tile * 64 + r;
      const float* src = ctxg + ((size_t)b * 257 + srow) * HH;
      const bool sv = (srow < nst);
#pragma unroll
      for (int u = 0; u < 8; ++u) {
        const int c = c0 + u * 2;
        float2 v = make_float2(0.f, 0.f);
        if (sv && c < HH) v = *reinterpret_cast<const float2*>(src + c);
        *reinterpret_cast<float2*>(&ct[r * 66 + c]) = v;
      }
    }
    {
      for (int i = tid; i < KK * 64; i += 256) {
        const int k = i >> 6, sl = i & 63;
        const int s = tile * 64 + sl;
        k_l[k * 68 + sl] =
            (s <= TT) ? kqg[((size_t)b * 10 + k) * 257 + s] : 0.f;
      }
    }
    __syncthreads();

    if (tile * 64 <= tw + 16) {
#pragma unroll 1
      for (int su16 = 0; su16 < 4; ++su16) {
        const int sb = tile * 64 + su16 * 16;
        if (sb > tw + 16) break;

        half4 kf;
#pragma unroll
        for (int i = 0; i < 4; ++i)
          kf[i] = (_Float16)k_l[(4 * lgrp + i) * 68 + su16 * 16 + lrow];

        const f32x4 sc =
            __builtin_amdgcn_mfma_f32_16x16x16f16(kf, qf, zf, 0, 0, 0);

        half4 pa;
#pragma unroll
        for (int r = 0; r < 4; ++r) {
          const int s = sb + 4 * lgrp + r;
          const float p = (s <= tw + lrow + 1) ? __expf(sc[r]) : 0.f;
          su += p;
          pa[r] = (_Float16)p;
        }

        const int vbase = su16 * 16 + 4 * lgrp;
#define PVHT(HT, ACC)                                                     \
  {                                                                       \
    half4 vf;                                                             \
    vf[0] = (_Float16)ct[(vbase + 0) * 66 + lrow + 16 * HT];              \
    vf[1] = (_Float16)ct[(vbase + 1) * 66 + lrow + 16 * HT];              \
    vf[2] = (_Float16)ct[(vbase + 2) * 66 + lrow + 16 * HT];              \
    vf[3] = (_Float16)ct[(vbase + 3) * 66 + lrow + 16 * HT];              \
    ACC = __builtin_amdgcn_mfma_f32_16x16x16f16(pa, vf, ACC, 0, 0, 0);    \
  }
        PVHT(0, acc0) PVHT(1, acc1) PVHT(2, acc2) PVHT(3, acc3)
      }
    }
  }

  su += __shfl_xor(su, 16, 64);
  su += __shfl_xor(su, 32, 64);
  if (lane < 16) su_l[wave * 16 + lane] = su;

#pragma unroll
  for (int r = 0; r < 4; ++r) {
    const int trow = wave * 16 + 4 * lgrp + r;
    o_l[trow * 66 + lrow + 0] = acc0[r];
    o_l[trow * 66 + lrow + 16] = acc1[r];
    o_l[trow * 66 + lrow + 32] = acc2[r];
    o_l[trow * 66 + lrow + 48] = acc3[r];
  }
  __syncthreads();

  {
    const int tl = tid >> 2;
    const int a = tid & 3;
    const float inv = 1.f / su_l[tl];
    const float* orow = &o_l[tl * 66];
    const float* wrow = W_act + a * HH;
    float s0 = 0.f, s1 = 0.f;
#pragma unroll
    for (int h = 0; h < HH; h += 2) {
      s0 = fmaf(orow[h], wrow[h], s0);
      s1 = fmaf(orow[h + 1], wrow[h + 1], s1);
    }
    out[((size_t)(tbase + tl) * BB + b) * AA + a] =
        fmaf(s0 + s1, inv, b_act[a]);
  }
}

extern "C" void kernel_launch(void* const* d_in, const int* in_sizes, int n_in,
                              void* d_out, int out_size, void* d_ws,
                              size_t ws_size, hipStream_t stream) {
  const float* x = (const float*)d_in[0];
  const float* W_in = (const float*)d_in[1];
  const float* b_in = (const float*)d_in[2];
  const float* W_ctx = (const float*)d_in[3];
  const float* b_ctx = (const float*)d_in[4];
  const float* W_key = (const float*)d_in[5];
  const float* b_key = (const float*)d_in[6];
  const float* W_q = (const float*)d_in[7];
  const float* b_q = (const float*)d_in[8];
  const float* fc = (const float*)d_in[9];
  const float* W_act = (const float*)d_in[10];
  const float* b_act = (const float*)d_in[11];
  float* out = (float*)d_out;
  float* ws = (float*)d_ws;

  float* WT = ws;                                   // 128*52
  float* WHT = ws + 8192;                           // 50*52
  float* WK2T = ws + 12288;                         // 50*64
  float* bias2 = ws + 15616;                        // 64
  _Float16* gh = (_Float16*)(ws + 16384);           // 131072*64 f16 = 4,194,304 floats
  float* hbufT = ws + 16384 + 4194304;              // 50*131072 f32
  float* ctxg = hbufT;                              // alias: dead after k1b (512*257*50)
  float* kqg = ctxg + (size_t)BB * 257 * HH;        // 512*10*257
  // total ~48.4 MB

  hipLaunchKernelGGL(k0_prep, dim3(26), dim3(256), 0, stream, W_in, W_ctx,
                     W_key, W_q, b_key, b_q, WT, WHT, WK2T, bias2);
  hipLaunchKernelGGL(k1a, dim3(512), dim3(256), 0, stream, x, WT, b_in, hbufT);
  hipLaunchKernelGGL(k1b, dim3(512), dim3(256), 0, stream, hbufT, WHT, b_ctx,
                     gh);
  hipLaunchKernelGGL(k2_mfma, dim3(32), dim3(64), 0, stream, gh, WK2T, bias2,
                     fc, ctxg, kqg);
  hipLaunchKernelGGL(k3_attn, dim3(2048), dim3(256), 0, stream, ctxg, kqg,
                     W_act, b_act, out);
}